// Round 14
// baseline (656.120 us; speedup 1.0000x reference)
//
#include <hip/hip_runtime.h>
#include <math.h>

#define TAUF 0.9f

typedef unsigned int u32;
typedef unsigned short ushort;
typedef __attribute__((ext_vector_type(8))) short short8;
typedef __attribute__((ext_vector_type(8))) _Float16 half8;
typedef __attribute__((ext_vector_type(4))) float f32x4;
typedef __attribute__((ext_vector_type(4))) unsigned short us4;
typedef __attribute__((ext_vector_type(8))) unsigned short us8;

__device__ __forceinline__ ushort f2bf(float f) {
  u32 u = __builtin_bit_cast(u32, f);
  u32 r = (u + 0x7FFFu + ((u >> 16) & 1u)) >> 16;
  return (ushort)r;
}
__device__ __forceinline__ float bf2f(ushort s) {
  u32 u = ((u32)s) << 16;
  return __builtin_bit_cast(float, u);
}

// exact-form GELU via A&S 7.1.26 erf approx (|erf err| < 1.5e-7)
__device__ __forceinline__ float gelu_f(float x) {
  float z = x * 0.70710678118654752f;
  float az = fabsf(z);
  float t = 1.f / fmaf(0.3275911f, az, 1.f);
  float poly = t * fmaf(t, fmaf(t, fmaf(t, fmaf(t, 1.061405429f, -1.453152027f),
                                        1.421413741f), -0.284496736f), 0.254829592f);
  float erfa = fmaf(-poly, __expf(-az * az), 1.f);
  float s = (z < 0.f) ? -erfa : erfa;
  return 0.5f * x * (1.f + s);
}

__device__ __forceinline__ void gload16(const void* g, void* l) {
  __builtin_amdgcn_global_load_lds(
      (const __attribute__((address_space(1))) u32*)g,
      (__attribute__((address_space(3))) u32*)l, 16, 0, 0);
}

// ---------- split-f16 input GEMM: h = relu(X @ Wi + bi), exact to ~f32 -------
__launch_bounds__(256, 2)
__global__ void gemm_in_mfma(const float* __restrict__ X,
                             const _Float16* __restrict__ Bh, const _Float16* __restrict__ Bl,
                             const float* __restrict__ bias, const float* __restrict__ Wa,
                             const float* __restrict__ wp, const float* __restrict__ g1,
                             const float* __restrict__ b1g, ushort* __restrict__ hb,
                             ushort* __restrict__ hn, float* __restrict__ delta,
                             float* __restrict__ adst, float* __restrict__ asrc,
                             float* __restrict__ xwp, int M) {
  __shared__ char lds[81920];  // Ah 8K | Al 8K | Bh 32K | Bl 32K
  char* As_h = lds;
  char* As_l = lds + 8192;
  char* Bs_h = lds + 16384;
  char* Bs_l = lds + 49152;
  const int tid = threadIdx.x;
  const int wave = tid >> 6, lane = tid & 63;
  const int bm = blockIdx.x * 64;

  const int arow = tid >> 2;
  const int ac4 = tid & 3;
  const int aoff0 = arow * 128 + (((2 * ac4 + 0) ^ (arow & 7)) << 4);
  const int aoff1 = arow * 128 + (((2 * ac4 + 1) ^ (arow & 7)) << 4);
  const int srow = lane >> 3;
  const int scol = (((lane & 7) ^ srow) << 3);

  f32x4 accH[4][4], accC[4][4];
#pragma unroll
  for (int i = 0; i < 4; ++i)
#pragma unroll
    for (int j = 0; j < 4; ++j) {
      accH[i][j] = (f32x4){0.f, 0.f, 0.f, 0.f};
      accC[i][j] = (f32x4){0.f, 0.f, 0.f, 0.f};
    }

  int ar = bm + arow;
  ar = (ar < M) ? ar : (M - 1);
  const float* xrow = X + (size_t)ar * 256 + ac4 * 16;

#pragma unroll
  for (int k0 = 0; k0 < 256; k0 += 64) {
    float4 x0 = *reinterpret_cast<const float4*>(xrow + k0);
    float4 x1 = *reinterpret_cast<const float4*>(xrow + k0 + 4);
    float4 x2 = *reinterpret_cast<const float4*>(xrow + k0 + 8);
    float4 x3 = *reinterpret_cast<const float4*>(xrow + k0 + 12);
    float xs[16] = {x0.x, x0.y, x0.z, x0.w, x1.x, x1.y, x1.z, x1.w,
                    x2.x, x2.y, x2.z, x2.w, x3.x, x3.y, x3.z, x3.w};
    half8 hh0, hh1, ll0, ll1;
#pragma unroll
    for (int j = 0; j < 8; ++j) {
      _Float16 hv = (_Float16)xs[j];
      hh0[j] = hv;
      ll0[j] = (_Float16)((xs[j] - (float)hv) * 2048.f);
      _Float16 hv2 = (_Float16)xs[8 + j];
      hh1[j] = hv2;
      ll1[j] = (_Float16)((xs[8 + j] - (float)hv2) * 2048.f);
    }
    *reinterpret_cast<half8*>(As_h + aoff0) = hh0;
    *reinterpret_cast<half8*>(As_h + aoff1) = hh1;
    *reinterpret_cast<half8*>(As_l + aoff0) = ll0;
    *reinterpret_cast<half8*>(As_l + aoff1) = ll1;
#pragma unroll
    for (int r = 0; r < 8; ++r) {
      const int ch = r * 4 + wave;
      const int br = ch * 8 + srow;
      gload16(Bh + (size_t)br * 256 + k0 + scol, Bs_h + ch * 1024);
      gload16(Bl + (size_t)br * 256 + k0 + scol, Bs_l + ch * 1024);
    }
    __syncthreads();
#pragma unroll
    for (int kk = 0; kk < 2; ++kk) {
      const int c = (kk * 32 + (lane >> 4) * 8) * 2;
      half8 ah[4], al[4];
#pragma unroll
      for (int mi = 0; mi < 4; ++mi) {
        const int rr = mi * 16 + (lane & 15);
        const int off = rr * 128 + (c ^ ((rr & 7) << 4));
        ah[mi] = *(const half8*)(As_h + off);
        al[mi] = *(const half8*)(As_l + off);
      }
#pragma unroll
      for (int ni = 0; ni < 4; ++ni) {
        const int rr = wave * 64 + ni * 16 + (lane & 15);
        half8 bh = *(const half8*)(Bs_h + rr * 128 + (c ^ ((rr & 7) << 4)));
#pragma unroll
        for (int mi = 0; mi < 4; ++mi)
          accH[mi][ni] = __builtin_amdgcn_mfma_f32_16x16x32_f16(ah[mi], bh,
                                                                accH[mi][ni], 0, 0, 0);
#pragma unroll
        for (int mi = 0; mi < 4; ++mi)
          accC[mi][ni] = __builtin_amdgcn_mfma_f32_16x16x32_f16(al[mi], bh,
                                                                accC[mi][ni], 0, 0, 0);
      }
#pragma unroll
      for (int ni = 0; ni < 4; ++ni) {
        const int rr = wave * 64 + ni * 16 + (lane & 15);
        half8 bl = *(const half8*)(Bs_l + rr * 128 + (c ^ ((rr & 7) << 4)));
#pragma unroll
        for (int mi = 0; mi < 4; ++mi)
          accC[mi][ni] = __builtin_amdgcn_mfma_f32_16x16x32_f16(ah[mi], bl,
                                                                accC[mi][ni], 0, 0, 0);
      }
    }
    __syncthreads();
  }

  float bb[4], wa0[4], wa1[4], wpv[4], gg[4], gb[4];
#pragma unroll
  for (int ni = 0; ni < 4; ++ni) {
    const int c = wave * 64 + ni * 16 + (lane & 15);
    bb[ni] = bias[c]; wa0[ni] = Wa[c]; wa1[ni] = Wa[256 + c];
    wpv[ni] = wp[c]; gg[ni] = g1[c]; gb[ni] = b1g[c];
  }
  float* red = (float*)lds;              // [5][4 waves][64 rows] = 5120 B
  float* muA = (float*)(lds + 5120);
  float* isA = (float*)(lds + 5376);
  const float inv = 1.f / 2048.f;
#pragma unroll
  for (int mi = 0; mi < 4; ++mi) {
#pragma unroll
    for (int reg = 0; reg < 4; ++reg) {
      const int lrow = mi * 16 + (lane >> 4) * 4 + reg;
      const int row = bm + lrow;
      float v[4];
      float p0 = 0.f, p1 = 0.f, p2 = 0.f, p3 = 0.f, p4 = 0.f;
#pragma unroll
      for (int ni = 0; ni < 4; ++ni) {
        float t = accH[mi][ni][reg] + accC[mi][ni][reg] * inv + bb[ni];
        t = fmaxf(t, 0.f);
        v[ni] = t;
        p0 += t; p1 += t * wa0[ni]; p2 += t * wa1[ni]; p3 += t * wpv[ni];
        p4 += t * t;
      }
      if (row < M) {
#pragma unroll
        for (int ni = 0; ni < 4; ++ni)
          hb[(size_t)row * 256 + wave * 64 + ni * 16 + (lane & 15)] = f2bf(v[ni]);
      }
#pragma unroll
      for (int ni = 0; ni < 4; ++ni) accH[mi][ni][reg] = v[ni];
#pragma unroll
      for (int off = 1; off < 16; off <<= 1) {
        p0 += __shfl_xor(p0, off, 64);
        p1 += __shfl_xor(p1, off, 64);
        p2 += __shfl_xor(p2, off, 64);
        p3 += __shfl_xor(p3, off, 64);
        p4 += __shfl_xor(p4, off, 64);
      }
      if ((lane & 15) == 0) {
        red[(0 * 4 + wave) * 64 + lrow] = p0;
        red[(1 * 4 + wave) * 64 + lrow] = p1;
        red[(2 * 4 + wave) * 64 + lrow] = p2;
        red[(3 * 4 + wave) * 64 + lrow] = p3;
        red[(4 * 4 + wave) * 64 + lrow] = p4;
      }
    }
  }
  __syncthreads();
  if (tid < 64) {
    float s0 = 0.f, s1 = 0.f, s2 = 0.f, s3 = 0.f, s4 = 0.f;
#pragma unroll
    for (int w = 0; w < 4; ++w) {
      s0 += red[(0 * 4 + w) * 64 + tid];
      s1 += red[(1 * 4 + w) * 64 + tid];
      s2 += red[(2 * 4 + w) * 64 + tid];
      s3 += red[(3 * 4 + w) * 64 + tid];
      s4 += red[(4 * 4 + w) * 64 + tid];
    }
    const int row = bm + tid;
    if (row < M) {
      delta[row] = s0; adst[row] = s1; asrc[row] = s2; xwp[row] = s3;
    }
    float mu = s0 * (1.f / 256.f);
    muA[tid] = mu;
    isA[tid] = rsqrtf(s4 * (1.f / 256.f) - mu * mu + 1e-5f);
  }
  __syncthreads();
#pragma unroll
  for (int mi = 0; mi < 4; ++mi) {
#pragma unroll
    for (int reg = 0; reg < 4; ++reg) {
      const int lrow = mi * 16 + (lane >> 4) * 4 + reg;
      const int row = bm + lrow;
      if (row >= M) continue;
      const float mu = muA[lrow], is = isA[lrow];
#pragma unroll
      for (int ni = 0; ni < 4; ++ni) {
        const int col = wave * 64 + ni * 16 + (lane & 15);
        hn[(size_t)row * 256 + col] = f2bf((accH[mi][ni][reg] - mu) * is * gg[ni] + gb[ni]);
      }
    }
  }
}

// -------- gather-average: hagg[d] = sum_j kw[d][j] * hn[ksrc[d][j]] ----------
__global__ void gather_k(const ushort* __restrict__ hn, const int* __restrict__ ksrc,
                         const float* __restrict__ kw, ushort* __restrict__ hagg, int N) {
  int d = blockIdx.x * 8 + (threadIdx.x >> 5);
  if (d >= N) return;
  int sub = threadIdx.x & 31;
  us8 xv[8];
  float w[8];
#pragma unroll
  for (int j = 0; j < 8; ++j) {
    int s = ksrc[(size_t)d * 8 + j];
    w[j] = kw[(size_t)d * 8 + j];
    xv[j] = *reinterpret_cast<const us8*>(hn + (size_t)s * 256 + sub * 8);
  }
  float a[8] = {0.f, 0.f, 0.f, 0.f, 0.f, 0.f, 0.f, 0.f};
#pragma unroll
  for (int j = 0; j < 8; ++j)
#pragma unroll
    for (int q = 0; q < 8; ++q) a[q] += w[j] * bf2f(xv[j][q]);
  us8 o;
#pragma unroll
  for (int q = 0; q < 8; ++q) o[q] = f2bf(a[q]);
  *reinterpret_cast<us8*>(hagg + (size_t)d * 256 + sub * 8) = o;
}

// ---- conv + agg + residual + LN2, fused: 8 waves, BM=128, BN=256, K=256 -----
__launch_bounds__(512, 4)
__global__ void gemm_conv_aggln(const ushort* __restrict__ A, const ushort* __restrict__ Bt,
                                const float* __restrict__ bias, const float* __restrict__ g2,
                                const float* __restrict__ b2g, ushort* __restrict__ hb,
                                ushort* __restrict__ hn, int M) {
  __shared__ ushort As[128 * 64];   // 16 KB
  __shared__ ushort Bs[256 * 64];   // 32 KB
  const int tid = threadIdx.x;
  const int wave = tid >> 6, lane = tid & 63;
  const int bm = blockIdx.x * 128;
  const int wm = (wave >> 2) * 64, wn = (wave & 3) * 64;
  const int srow = lane >> 3;
  const int scol = (((lane & 7) ^ srow) << 3);

  f32x4 acc[4][4];
#pragma unroll
  for (int i = 0; i < 4; ++i)
#pragma unroll
    for (int j = 0; j < 4; ++j) acc[i][j] = (f32x4){0.f, 0.f, 0.f, 0.f};

  for (int k0 = 0; k0 < 256; k0 += 64) {
#pragma unroll
    for (int r = 0; r < 2; ++r) {
      const int ch = r * 8 + wave;
      int ar = bm + ch * 8 + srow;
      ar = (ar < M) ? ar : (M - 1);
      gload16(A + (size_t)ar * 256 + k0 + scol, (char*)As + ch * 1024);
    }
#pragma unroll
    for (int r = 0; r < 4; ++r) {
      const int ch = r * 8 + wave;
      const int br = ch * 8 + srow;
      gload16(Bt + (size_t)br * 256 + k0 + scol, (char*)Bs + ch * 1024);
    }
    __syncthreads();
#pragma unroll
    for (int kk = 0; kk < 2; ++kk) {
      const int c = (kk * 32 + (lane >> 4) * 8) * 2;
      short8 a[4];
#pragma unroll
      for (int mi = 0; mi < 4; ++mi) {
        const int rr = wm + mi * 16 + (lane & 15);
        a[mi] = *(const short8*)((const char*)As + rr * 128 + (c ^ ((rr & 7) << 4)));
      }
#pragma unroll
      for (int ni = 0; ni < 4; ++ni) {
        const int rr = wn + ni * 16 + (lane & 15);
        short8 b = *(const short8*)((const char*)Bs + rr * 128 + (c ^ ((rr & 7) << 4)));
#pragma unroll
        for (int mi = 0; mi < 4; ++mi)
          acc[mi][ni] = __builtin_amdgcn_mfma_f32_16x16x32_bf16(a[mi], b,
                                                                acc[mi][ni], 0, 0, 0);
      }
    }
    __syncthreads();
  }

  float bb[4];
#pragma unroll
  for (int ni = 0; ni < 4; ++ni) bb[ni] = bias[wn + ni * 16 + (lane & 15)];

  float* redS = (float*)As;            // [4 n-waves][128 rows]
  float* redQ = redS + 512;
  float* muA  = redQ + 512;            // [128]
  float* isA  = muA + 128;             // [128]

#pragma unroll
  for (int mi = 0; mi < 4; ++mi) {
#pragma unroll
    for (int reg = 0; reg < 4; ++reg) {
      const int lrow = wm + mi * 16 + (lane >> 4) * 4 + reg;
      const int row = bm + lrow;
      const bool ok = (row < M);
      float pS = 0.f, pQ = 0.f;
#pragma unroll
      for (int ni = 0; ni < 4; ++ni) {
        const int col = wn + ni * 16 + (lane & 15);
        float t = fmaxf(acc[mi][ni][reg] + bb[ni], 0.f);
        if (ok) {
          t += bf2f(hb[(size_t)row * 256 + col]);
          hb[(size_t)row * 256 + col] = f2bf(t);
        }
        acc[mi][ni][reg] = t;
        pS += t;
        pQ += t * t;
      }
#pragma unroll
      for (int off = 1; off < 16; off <<= 1) {
        pS += __shfl_xor(pS, off, 64);
        pQ += __shfl_xor(pQ, off, 64);
      }
      if ((lane & 15) == 0) {
        redS[(wave & 3) * 128 + lrow] = pS;
        redQ[(wave & 3) * 128 + lrow] = pQ;
      }
    }
  }
  __syncthreads();
  if (tid < 128) {
    float S = redS[tid] + redS[128 + tid] + redS[256 + tid] + redS[384 + tid];
    float Q = redQ[tid] + redQ[128 + tid] + redQ[256 + tid] + redQ[384 + tid];
    float mu = S * (1.f / 256.f);
    muA[tid] = mu;
    isA[tid] = rsqrtf(Q * (1.f / 256.f) - mu * mu + 1e-5f);
  }
  __syncthreads();
  float gg[4], gb[4];
#pragma unroll
  for (int ni = 0; ni < 4; ++ni) {
    gg[ni] = g2[wn + ni * 16 + (lane & 15)];
    gb[ni] = b2g[wn + ni * 16 + (lane & 15)];
  }
#pragma unroll
  for (int mi = 0; mi < 4; ++mi) {
#pragma unroll
    for (int reg = 0; reg < 4; ++reg) {
      const int lrow = wm + mi * 16 + (lane >> 4) * 4 + reg;
      const int row = bm + lrow;
      if (row >= M) continue;
      const float mu = muA[lrow], is = isA[lrow];
#pragma unroll
      for (int ni = 0; ni < 4; ++ni) {
        const int col = wn + ni * 16 + (lane & 15);
        hn[(size_t)row * 256 + col] = f2bf((acc[mi][ni][reg] - mu) * is * gg[ni] + gb[ni]);
      }
    }
  }
}

// ======== FUSED FFN: h' = h + gelu(hn@W1+b1)@W2 + b2; LN1_{l+1} or store =====
// Per 128-row block, loop 8 eighths of the 512 hidden dim. Per eighth:
//   ffn1 sub-GEMM with SWAPPED operands (A=W1T slice, B=hn rows) so each
//   lane's 4 regs are consecutive u-cols -> b64 writes into Uq (XOR-swizzled);
//   then one K=64 ffn2 partial from Uq accumulating acc2.
// u never touches global. hn written in-place in epilogue (each block only
// reads/writes its own 128 rows; writes happen after all reads).
template <int LAST>
__launch_bounds__(512, 4)
__global__ void gemm_ffn(const ushort* __restrict__ hn, const ushort* __restrict__ W1T,
                         const float* __restrict__ b1, const ushort* __restrict__ W2T,
                         const float* __restrict__ b2, const float* __restrict__ g1,
                         const float* __restrict__ b1g, ushort* __restrict__ hb,
                         ushort* __restrict__ hn_out, int M) {
  __shared__ ushort Hs[128 * 64];   // hn chunk: 128 rows x 64 K  (16 KB)
  __shared__ ushort Bs[256 * 64];   // W1 (8KB used) / W2 (32KB) staging
  __shared__ ushort Uq[128 * 64];   // u eighth: [row][ucol]      (16 KB)
  const int tid = threadIdx.x;
  const int wave = tid >> 6, lane = tid & 63;
  const int bm = blockIdx.x * 128;
  const int wm1 = (wave >> 2) * 32, wn1 = (wave & 3) * 32;   // ffn1: [32 uc][32 rows]
  const int wm2 = (wave >> 2) * 64, wn2 = (wave & 3) * 64;   // ffn2: [64 rows][64 oc]
  const int srow = lane >> 3;
  const int scol = (((lane & 7) ^ srow) << 3);

  f32x4 acc2[4][4];
#pragma unroll
  for (int i = 0; i < 4; ++i)
#pragma unroll
    for (int j = 0; j < 4; ++j) acc2[i][j] = (f32x4){0.f, 0.f, 0.f, 0.f};

  for (int e = 0; e < 8; ++e) {
    const int E = e * 64;
    f32x4 acc1[2][2];
#pragma unroll
    for (int i = 0; i < 2; ++i)
#pragma unroll
      for (int j = 0; j < 2; ++j) acc1[i][j] = (f32x4){0.f, 0.f, 0.f, 0.f};

    // ---- ffn1 sub-GEMM: C[ucol][row] over K=256 ----
    for (int ks = 0; ks < 4; ++ks) {
      const int k0 = ks * 64;
      // stage hn rows (128 x 64K = 16 chunks, 2/wave)
#pragma unroll
      for (int r = 0; r < 2; ++r) {
        const int ch = r * 8 + wave;
        int ar = bm + ch * 8 + srow;
        ar = (ar < M) ? ar : (M - 1);
        gload16(hn + (size_t)ar * 256 + k0 + scol, (char*)Hs + ch * 1024);
      }
      // stage W1 slice (64 ucols x 64K = 8 chunks, 1/wave)
      {
        const int ur = E + wave * 8 + srow;
        gload16(W1T + (size_t)ur * 256 + k0 + scol, (char*)Bs + wave * 1024);
      }
      __syncthreads();
#pragma unroll
      for (int kk = 0; kk < 2; ++kk) {
        const int c = (kk * 32 + (lane >> 4) * 8) * 2;
        short8 bfrag[2];
#pragma unroll
        for (int ni = 0; ni < 2; ++ni) {
          const int rr = wn1 + ni * 16 + (lane & 15);
          bfrag[ni] = *(const short8*)((const char*)Hs + rr * 128 + (c ^ ((rr & 7) << 4)));
        }
#pragma unroll
        for (int mi = 0; mi < 2; ++mi) {
          const int rr = wm1 + mi * 16 + (lane & 15);
          short8 a = *(const short8*)((const char*)Bs + rr * 128 + (c ^ ((rr & 7) << 4)));
#pragma unroll
          for (int ni = 0; ni < 2; ++ni)
            acc1[mi][ni] = __builtin_amdgcn_mfma_f32_16x16x32_bf16(a, bfrag[ni],
                                                                   acc1[mi][ni], 0, 0, 0);
        }
      }
      __syncthreads();
    }
    // ---- gelu + pack -> Uq (b64 writes; slot = uc>>3 ^ (row&7)) ----
#pragma unroll
    for (int mi = 0; mi < 2; ++mi) {
#pragma unroll
      for (int ni = 0; ni < 2; ++ni) {
        const int ucb = wm1 + mi * 16 + (lane >> 4) * 4;
        const int hrow = wn1 + ni * 16 + (lane & 15);
        us4 pk;
#pragma unroll
        for (int reg = 0; reg < 4; ++reg)
          pk[reg] = f2bf(gelu_f(acc1[mi][ni][reg] + b1[E + ucb + reg]));
        const int slot = ucb >> 3, half = (ucb >> 2) & 1;
        *reinterpret_cast<us4*>((char*)Uq + hrow * 128 +
                                ((slot ^ (hrow & 7)) << 4) + half * 8) = pk;
      }
    }
    // ---- ffn2 partial: K-slice = this eighth (64) ----
#pragma unroll
    for (int r = 0; r < 4; ++r) {
      const int ch = r * 8 + wave;
      const int oc = ch * 8 + srow;
      gload16(W2T + (size_t)oc * 512 + E + scol, (char*)Bs + ch * 1024);
    }
    __syncthreads();   // fences Uq writes + W2 staging
#pragma unroll
    for (int kk = 0; kk < 2; ++kk) {
      const int c = (kk * 32 + (lane >> 4) * 8) * 2;
      short8 a[4];
#pragma unroll
      for (int mi = 0; mi < 4; ++mi) {
        const int rr = wm2 + mi * 16 + (lane & 15);
        const int slot = kk * 4 + (lane >> 4);
        a[mi] = *(const short8*)((const char*)Uq + rr * 128 + ((slot ^ (rr & 7)) << 4));
      }
#pragma unroll
      for (int ni = 0; ni < 4; ++ni) {
        const int rr = wn2 + ni * 16 + (lane & 15);
        short8 b = *(const short8*)((const char*)Bs + rr * 128 + (c ^ ((rr & 7) << 4)));
#pragma unroll
        for (int mi = 0; mi < 4; ++mi)
          acc2[mi][ni] = __builtin_amdgcn_mfma_f32_16x16x32_bf16(a[mi], b,
                                                                 acc2[mi][ni], 0, 0, 0);
      }
    }
    __syncthreads();
  }

  // ---- epilogue: bias + residual (hb RMW) + LN1_{l+1} (or LAST store) ----
  float bb[4];
#pragma unroll
  for (int ni = 0; ni < 4; ++ni) bb[ni] = b2[wn2 + ni * 16 + (lane & 15)];

  float* redS = (float*)Hs;            // [4 n-waves][128 rows]
  float* redQ = redS + 512;
  float* muA  = redQ + 512;            // [128]
  float* isA  = muA + 128;             // [128]

#pragma unroll
  for (int mi = 0; mi < 4; ++mi) {
#pragma unroll
    for (int reg = 0; reg < 4; ++reg) {
      const int lrow = wm2 + mi * 16 + (lane >> 4) * 4 + reg;
      const int row = bm + lrow;
      const bool ok = (row < M);
      float pS = 0.f, pQ = 0.f;
#pragma unroll
      for (int ni = 0; ni < 4; ++ni) {
        const int col = wn2 + ni * 16 + (lane & 15);
        float t = acc2[mi][ni][reg] + bb[ni];
        if (ok) t += bf2f(hb[(size_t)row * 256 + col]);
        acc2[mi][ni][reg] = t;
        if (LAST) {
          if (ok) hn_out[(size_t)row * 256 + col] = f2bf(t);
        } else {
          if (ok) hb[(size_t)row * 256 + col] = f2bf(t);
          pS += t;
          pQ += t * t;
        }
      }
      if (!LAST) {
#pragma unroll
        for (int off = 1; off < 16; off <<= 1) {
          pS += __shfl_xor(pS, off, 64);
          pQ += __shfl_xor(pQ, off, 64);
        }
        if ((lane & 15) == 0) {
          redS[(wave & 3) * 128 + lrow] = pS;
          redQ[(wave & 3) * 128 + lrow] = pQ;
        }
      }
    }
  }
  if (LAST) return;
  __syncthreads();
  if (tid < 128) {
    float S = redS[tid] + redS[128 + tid] + redS[256 + tid] + redS[384 + tid];
    float Q = redQ[tid] + redQ[128 + tid] + redQ[256 + tid] + redQ[384 + tid];
    float mu = S * (1.f / 256.f);
    muA[tid] = mu;
    isA[tid] = rsqrtf(Q * (1.f / 256.f) - mu * mu + 1e-5f);
  }
  __syncthreads();
  float gg[4], gb[4];
#pragma unroll
  for (int ni = 0; ni < 4; ++ni) {
    gg[ni] = g1[wn2 + ni * 16 + (lane & 15)];
    gb[ni] = b1g[wn2 + ni * 16 + (lane & 15)];
  }
#pragma unroll
  for (int mi = 0; mi < 4; ++mi) {
#pragma unroll
    for (int reg = 0; reg < 4; ++reg) {
      const int lrow = wm2 + mi * 16 + (lane >> 4) * 4 + reg;
      const int row = bm + lrow;
      if (row >= M) continue;
      const float mu = muA[lrow], is = isA[lrow];
#pragma unroll
      for (int ni = 0; ni < 4; ++ni) {
        const int col = wn2 + ni * 16 + (lane & 15);
        hn_out[(size_t)row * 256 + col] = f2bf((acc2[mi][ni][reg] - mu) * is * gg[ni] + gb[ni]);
      }
    }
  }
}

// ---------------- bf16 MFMA output GEMM: C(f32) = A @ Bt^T + bias ------------
__launch_bounds__(256)
__global__ void gemm_out(const ushort* __restrict__ A, const ushort* __restrict__ Bt,
                         const float* __restrict__ bias, float* __restrict__ C, int M) {
  __shared__ ushort As[128 * 64];
  __shared__ ushort Bs[64 * 64];
  const int tid = threadIdx.x;
  const int wave = tid >> 6, lane = tid & 63;
  const int bm = blockIdx.x * 128;
  const int wm = wave * 32;
  const int srow = lane >> 3;
  const int scol = (((lane & 7) ^ srow) << 3);
  f32x4 acc[2][4];
#pragma unroll
  for (int i = 0; i < 2; ++i)
#pragma unroll
    for (int j = 0; j < 4; ++j) acc[i][j] = (f32x4){0.f, 0.f, 0.f, 0.f};

  for (int k0 = 0; k0 < 256; k0 += 64) {
#pragma unroll
    for (int r = 0; r < 4; ++r) {
      const int ch = r * 4 + wave;
      int ar = bm + ch * 8 + srow;
      ar = (ar < M) ? ar : (M - 1);
      gload16(A + (size_t)ar * 256 + k0 + scol, (char*)As + ch * 1024);
    }
#pragma unroll
    for (int r = 0; r < 2; ++r) {
      const int ch = r * 4 + wave;
      const int br = ch * 8 + srow;
      gload16(Bt + (size_t)br * 256 + k0 + scol, (char*)Bs + ch * 1024);
    }
    __syncthreads();
#pragma unroll
    for (int kk = 0; kk < 2; ++kk) {
      const int c = (kk * 32 + (lane >> 4) * 8) * 2;
      short8 a[2], b[4];
#pragma unroll
      for (int mi = 0; mi < 2; ++mi) {
        const int rr = wm + mi * 16 + (lane & 15);
        a[mi] = *(const short8*)((const char*)As + rr * 128 + (c ^ ((rr & 7) << 4)));
      }
#pragma unroll
      for (int ni = 0; ni < 4; ++ni) {
        const int rr = ni * 16 + (lane & 15);
        b[ni] = *(const short8*)((const char*)Bs + rr * 128 + (c ^ ((rr & 7) << 4)));
      }
#pragma unroll
      for (int mi = 0; mi < 2; ++mi)
#pragma unroll
        for (int ni = 0; ni < 4; ++ni)
          acc[mi][ni] = __builtin_amdgcn_mfma_f32_16x16x32_bf16(a[mi], b[ni],
                                                                acc[mi][ni], 0, 0, 0);
    }
    __syncthreads();
  }
  float bb[4];
#pragma unroll
  for (int ni = 0; ni < 4; ++ni) bb[ni] = bias[ni * 16 + (lane & 15)];
#pragma unroll
  for (int mi = 0; mi < 2; ++mi) {
#pragma unroll
    for (int reg = 0; reg < 4; ++reg) {
      const int row = bm + wm + mi * 16 + (lane >> 4) * 4 + reg;
      if (row >= M) continue;
#pragma unroll
      for (int ni = 0; ni < 4; ++ni) {
        const int col = ni * 16 + (lane & 15);
        C[(size_t)row * 64 + col] = acc[mi][ni][reg] + bb[ni];
      }
    }
  }
}

// ---- one-shot prep: weight transposes/converts (incl. Wi f16 split) + zero --
#define W_IN 65536
#define W_TOTAL (196608 + 393216 + 393216 + 16384)
__global__ void prep_k(const float* __restrict__ Wi, const float* __restrict__ Wc,
                       const float* __restrict__ W1, const float* __restrict__ W2,
                       const float* __restrict__ Wo, _Float16* __restrict__ WiTh,
                       _Float16* __restrict__ WiTl, ushort* __restrict__ WcT,
                       ushort* __restrict__ W1T, ushort* __restrict__ W2T,
                       ushort* __restrict__ WoT, float* __restrict__ zbase, int zn) {
  int i = blockIdx.x * 256 + threadIdx.x;
  if (i < W_IN) {
    int n = i >> 8, k = i & 255;
    float w = Wi[(size_t)k * 256 + n];
    _Float16 hv = (_Float16)w;
    WiTh[i] = hv;
    WiTl[i] = (_Float16)((w - (float)hv) * 2048.f);
  } else if ((i -= W_IN) < W_TOTAL) {
    int j = i;
    if (j < 196608) {
      int l = j / 65536, r = j % 65536, n = r >> 8, k = r & 255;
      WcT[j] = f2bf(Wc[(size_t)l * 65536 + k * 256 + n]);
    } else if ((j -= 196608) < 393216) {
      int l = j / 131072, r = j % 131072, n = r >> 8, k = r & 255;
      W1T[j] = f2bf(W1[(size_t)l * 131072 + k * 512 + n]);
    } else if ((j -= 393216) < 393216) {
      int l = j / 131072, r = j % 131072, n = r >> 9, k = r & 511;
      W2T[j] = f2bf(W2[(size_t)l * 131072 + k * 256 + n]);
    } else {
      j -= 393216;
      int n = j >> 8, k = j & 255;
      WoT[j] = f2bf(Wo[k * 64 + n]);
    }
  } else {
    int z = i - W_TOTAL;
    if (z < zn) zbase[z] = 0.f;
  }
}

__global__ void neigh_k(const int* __restrict__ src, const int* __restrict__ dst,
                        const float* __restrict__ delta, float* __restrict__ neigh, int E) {
  int e = blockIdx.x * 256 + threadIdx.x;
  if (e < E) atomicAdd(&neigh[dst[e]], delta[src[e]]);
}

// edge logits (pi inline); slots layout [t][N]
__global__ void logits_k(const int* __restrict__ src, const int* __restrict__ dst,
                         const float* __restrict__ adst, const float* __restrict__ asrc,
                         const float* __restrict__ xwp, const float* __restrict__ neigh,
                         const float* __restrict__ Wa, const float* __restrict__ ba,
                         float* __restrict__ expe, float* __restrict__ denom,
                         int* __restrict__ cnt, int* __restrict__ slots,
                         int E, int Et, int N) {
  int e = blockIdx.x * 256 + threadIdx.x;
  if (e >= Et) return;
  int s, d;
  if (e < E) { s = src[e]; d = dst[e]; } else { s = e - E; d = s; }
  float pis = 1.f / (1.f + expf(-(xwp[s] + neigh[s])));
  float v = adst[d] + asrc[s] + pis * Wa[512] + ba[0];
  v = (v >= 0.f ? v : 0.2f * v) / TAUF;
  v = fminf(fmaxf(v, -5.f), 5.f);
  float ex = expf(v);
  expe[e] = ex;
  atomicAdd(&denom[d], ex);
  int p = atomicAdd(&cnt[d], 1);
  if (p < 64) slots[(size_t)p * N + d] = e;
}

__device__ __forceinline__ bool better(float a, int e, float a2, int e2) {
  return a > a2 || (a == a2 && e < e2);
}

// top-8 + renormalize; ksrc/kw padded to exactly 8 entries (w=0)
__global__ void topk_k(const int* __restrict__ cnt, const int* __restrict__ slots,
                       const float* __restrict__ expe, const float* __restrict__ denom,
                       const int* __restrict__ src, int* __restrict__ ksrc,
                       float* __restrict__ kw, int N, int E) {
  int d = blockIdx.x * 256 + threadIdx.x;
  if (d >= N) return;
  int deg = min(cnt[d], 64);
  float D = denom[d] + 1e-16f;
  float av[8]; int ai[8]; int kc = 0;
  for (int t = 0; t < deg; ++t) {
    int e = slots[(size_t)t * N + d];
    float a = expe[e] / D;
    if (kc < 8) {
      int p = kc++;
      while (p > 0 && better(a, e, av[p - 1], ai[p - 1])) {
        av[p] = av[p - 1]; ai[p] = ai[p - 1]; --p;
      }
      av[p] = a; ai[p] = e;
    } else if (better(a, e, av[7], ai[7])) {
      int p = 7;
      while (p > 0 && better(a, e, av[p - 1], ai[p - 1])) {
        av[p] = av[p - 1]; ai[p] = ai[p - 1]; --p;
      }
      av[p] = a; ai[p] = e;
    }
  }
  float ks = 0.f;
  for (int j = 0; j < kc; ++j) ks += av[j];
  float inv = 1.f / (ks + 1e-16f);
#pragma unroll
  for (int j = 0; j < 8; ++j) {
    if (j < kc) {
      int e = ai[j];
      ksrc[(size_t)d * 8 + j] = (e < E) ? src[e] : (e - E);
      kw[(size_t)d * 8 + j] = av[j] * inv;
    } else {
      ksrc[(size_t)d * 8 + j] = 0;
      kw[(size_t)d * 8 + j] = 0.f;
    }
  }
}

extern "C" void kernel_launch(void* const* d_in, const int* in_sizes, int n_in,
                              void* d_out, int out_size, void* d_ws, size_t ws_size,
                              hipStream_t stream) {
  const float* X   = (const float*)d_in[0];
  const int*   EI  = (const int*)d_in[1];
  const float* Wi  = (const float*)d_in[2];
  const float* bi  = (const float*)d_in[3];
  const float* wp  = (const float*)d_in[4];
  const float* Wa  = (const float*)d_in[5];
  const float* ba  = (const float*)d_in[6];
  const float* l1g = (const float*)d_in[7];
  const float* l1b = (const float*)d_in[8];
  const float* l2g = (const float*)d_in[9];
  const float* l2b = (const float*)d_in[10];
  const float* W1  = (const float*)d_in[11];
  const float* b1  = (const float*)d_in[12];
  const float* W2  = (const float*)d_in[13];
  const float* b2  = (const float*)d_in[14];
  const float* Wc  = (const float*)d_in[15];
  const float* bc  = (const float*)d_in[16];
  const float* Wo  = (const float*)d_in[17];
  const float* bo  = (const float*)d_in[18];

  const int N = in_sizes[0] / 256;
  const int E = in_sizes[1] / 2;
  const int Et = E + N;
  const int* srcp = EI;
  const int* dstp = EI + E;

  float* ws = (float*)d_ws;
  size_t off = 0;
  auto alloc = [&](size_t n) { float* p = ws + off; off += n; return p; };
  const size_t NH = (size_t)N * 256;
  ushort* hb   = (ushort*)alloc(NH / 2);               // bf16 residual [N][256]
  ushort* hn   = (ushort*)alloc(NH / 2);               // bf16 [N][256]
  ushort* hagg = (ushort*)alloc(NH / 2);               // bf16 [N][256]
  _Float16* WiTh = (_Float16*)alloc(65536 / 2);
  _Float16* WiTl = (_Float16*)alloc(65536 / 2);
  ushort* WcT  = (ushort*)alloc(3 * 65536 / 2);
  ushort* W1T  = (ushort*)alloc(3 * 131072 / 2);
  ushort* W2T  = (ushort*)alloc(3 * 131072 / 2);
  ushort* WoT  = (ushort*)alloc(16384 / 2);
  float* delta = alloc(N);
  float* adst  = alloc(N);
  float* asrc  = alloc(N);
  float* xwp   = alloc(N);
  float* expe  = alloc(Et);
  float* neigh = alloc(N);       // ┐ contiguous zero region (3N)
  float* denom = alloc(N);       // │
  int*   cnt   = (int*)alloc(N); // ┘
  int*   slots = (int*)alloc((size_t)N * 64);
  int*   ksrc  = (int*)alloc((size_t)N * 8);
  float* kw    = alloc((size_t)N * 8);

  prep_k<<<(W_IN + W_TOTAL + 3 * N + 255) / 256, 256, 0, stream>>>(
      Wi, Wc, W1, W2, Wo, WiTh, WiTl, WcT, W1T, W2T, WoT, neigh, 3 * N);

  // input projection + relu + row stats + LN1(l0); X split fused into staging
  gemm_in_mfma<<<(N + 63) / 64, 256, 0, stream>>>(
      X, WiTh, WiTl, bi, Wa, wp, l1g, l1b, hb, hn,
      delta, adst, asrc, xwp, N);
  neigh_k<<<(E + 255) / 256, 256, 0, stream>>>(srcp, dstp, delta, neigh, E);
  logits_k<<<(Et + 255) / 256, 256, 0, stream>>>(srcp, dstp, adst, asrc, xwp, neigh,
                                                 Wa, ba, expe, denom, cnt, slots,
                                                 E, Et, N);
  topk_k<<<(N + 255) / 256, 256, 0, stream>>>(cnt, slots, expe, denom, srcp,
                                              ksrc, kw, N, E);

  const int GM = (N + 127) / 128;
  for (int l = 0; l < 3; ++l) {
    gather_k<<<(N + 7) / 8, 256, 0, stream>>>(hn, ksrc, kw, hagg, N);
    gemm_conv_aggln<<<GM, 512, 0, stream>>>(
        hagg, WcT + (size_t)l * 65536, bc + l * 256,
        l2g + l * 256, l2b + l * 256, hb, hn, N);
    if (l < 2)
      gemm_ffn<0><<<GM, 512, 0, stream>>>(
          hn, W1T + (size_t)l * 131072, b1 + l * 512,
          W2T + (size_t)l * 131072, b2 + l * 256,
          l1g + (l + 1) * 256, l1b + (l + 1) * 256, hb, hn, N);
    else
      gemm_ffn<1><<<GM, 512, 0, stream>>>(
          hn, W1T + (size_t)l * 131072, b1 + l * 512,
          W2T + (size_t)l * 131072, b2 + l * 256,
          nullptr, nullptr, hb, hn, N);
  }
  gemm_out<<<(N + 127) / 128, 256, 0, stream>>>(hn, WoT, bo, (float*)d_out, N);
}

// Round 15
// 609.139 us; speedup vs baseline: 1.0771x; 1.0771x over previous
//
#include <hip/hip_runtime.h>
#include <math.h>

#define TAUF 0.9f

typedef unsigned int u32;
typedef unsigned short ushort;
typedef __attribute__((ext_vector_type(8))) short short8;
typedef __attribute__((ext_vector_type(8))) _Float16 half8;
typedef __attribute__((ext_vector_type(4))) float f32x4;
typedef __attribute__((ext_vector_type(4))) unsigned short us4;
typedef __attribute__((ext_vector_type(8))) unsigned short us8;

__device__ __forceinline__ ushort f2bf(float f) {
  u32 u = __builtin_bit_cast(u32, f);
  u32 r = (u + 0x7FFFu + ((u >> 16) & 1u)) >> 16;
  return (ushort)r;
}
__device__ __forceinline__ float bf2f(ushort s) {
  u32 u = ((u32)s) << 16;
  return __builtin_bit_cast(float, u);
}

// exact-form GELU via A&S 7.1.26 erf approx (|erf err| < 1.5e-7)
__device__ __forceinline__ float gelu_f(float x) {
  float z = x * 0.70710678118654752f;
  float az = fabsf(z);
  float t = 1.f / fmaf(0.3275911f, az, 1.f);
  float poly = t * fmaf(t, fmaf(t, fmaf(t, fmaf(t, 1.061405429f, -1.453152027f),
                                        1.421413741f), -0.284496736f), 0.254829592f);
  float erfa = fmaf(-poly, __expf(-az * az), 1.f);
  float s = (z < 0.f) ? -erfa : erfa;
  return 0.5f * x * (1.f + s);
}

__device__ __forceinline__ void gload16(const void* g, void* l) {
  __builtin_amdgcn_global_load_lds(
      (const __attribute__((address_space(1))) u32*)g,
      (__attribute__((address_space(3))) u32*)l, 16, 0, 0);
}

// ---------- split-f16 input GEMM: h = relu(X @ Wi + bi), exact to ~f32 -------
// 512 threads / 8 waves (each 32 rows x 64 cols: acc 64 VGPR not 128 ->
// fits (512,4) cap without R8-style spill). BK=64, 80KB LDS -> 2 blocks/CU
// = 4 waves/SIMD (vs 2 at 256thr) to hide barrier drains.
__launch_bounds__(512, 4)
__global__ void gemm_in_mfma(const float* __restrict__ X,
                             const _Float16* __restrict__ Bh, const _Float16* __restrict__ Bl,
                             const float* __restrict__ bias, const float* __restrict__ Wa,
                             const float* __restrict__ wp, const float* __restrict__ g1,
                             const float* __restrict__ b1g, ushort* __restrict__ hb,
                             ushort* __restrict__ hn, float* __restrict__ delta,
                             float* __restrict__ adst, float* __restrict__ asrc,
                             float* __restrict__ xwp, int M) {
  __shared__ char lds[81920];  // Ah 8K | Al 8K | Bh 32K | Bl 32K
  char* As_h = lds;
  char* As_l = lds + 8192;
  char* Bs_h = lds + 16384;
  char* Bs_l = lds + 49152;
  const int tid = threadIdx.x;
  const int wave = tid >> 6, lane = tid & 63;
  const int bm = blockIdx.x * 64;
  const int wm = (wave >> 2) * 32, wn = (wave & 3) * 64;

  // A staging: row = tid>>3 (0..63), chunk = tid&7 (8 f32 each)
  const int arow = tid >> 3;
  const int ac = tid & 7;
  const int aoff = arow * 128 + ((ac ^ (arow & 7)) << 4);
  // B staging (gload16): chunk = 8 rows x 128B; pre-swizzled global col
  const int srow = lane >> 3;
  const int scol = (((lane & 7) ^ srow) << 3);

  f32x4 accH[2][4], accC[2][4];
#pragma unroll
  for (int i = 0; i < 2; ++i)
#pragma unroll
    for (int j = 0; j < 4; ++j) {
      accH[i][j] = (f32x4){0.f, 0.f, 0.f, 0.f};
      accC[i][j] = (f32x4){0.f, 0.f, 0.f, 0.f};
    }

  int ar = bm + arow;
  ar = (ar < M) ? ar : (M - 1);
  const float* xrow = X + (size_t)ar * 256 + ac * 8;

#pragma unroll
  for (int k0 = 0; k0 < 256; k0 += 64) {
    // A: 8 f32 -> split -> half8 hi + half8 lo, swizzled ds_write
    float4 x0 = *reinterpret_cast<const float4*>(xrow + k0);
    float4 x1 = *reinterpret_cast<const float4*>(xrow + k0 + 4);
    float xs[8] = {x0.x, x0.y, x0.z, x0.w, x1.x, x1.y, x1.z, x1.w};
    half8 hh, ll;
#pragma unroll
    for (int j = 0; j < 8; ++j) {
      _Float16 hv = (_Float16)xs[j];
      hh[j] = hv;
      ll[j] = (_Float16)((xs[j] - (float)hv) * 2048.f);
    }
    *reinterpret_cast<half8*>(As_h + aoff) = hh;
    *reinterpret_cast<half8*>(As_l + aoff) = ll;
    // B: 32 chunks h + 32 chunks l across 8 waves (4 each)
#pragma unroll
    for (int r = 0; r < 4; ++r) {
      const int ch = r * 8 + wave;
      const int br = ch * 8 + srow;
      gload16(Bh + (size_t)br * 256 + k0 + scol, Bs_h + ch * 1024);
      gload16(Bl + (size_t)br * 256 + k0 + scol, Bs_l + ch * 1024);
    }
    __syncthreads();
#pragma unroll
    for (int kk = 0; kk < 2; ++kk) {
      const int c = (kk * 32 + (lane >> 4) * 8) * 2;
      half8 ah[2], al[2];
#pragma unroll
      for (int mi = 0; mi < 2; ++mi) {
        const int rr = wm + mi * 16 + (lane & 15);
        const int off = rr * 128 + (c ^ ((rr & 7) << 4));
        ah[mi] = *(const half8*)(As_h + off);
        al[mi] = *(const half8*)(As_l + off);
      }
#pragma unroll
      for (int ni = 0; ni < 4; ++ni) {
        const int rr = wn + ni * 16 + (lane & 15);
        half8 bh = *(const half8*)(Bs_h + rr * 128 + (c ^ ((rr & 7) << 4)));
#pragma unroll
        for (int mi = 0; mi < 2; ++mi)
          accH[mi][ni] = __builtin_amdgcn_mfma_f32_16x16x32_f16(ah[mi], bh,
                                                                accH[mi][ni], 0, 0, 0);
#pragma unroll
        for (int mi = 0; mi < 2; ++mi)
          accC[mi][ni] = __builtin_amdgcn_mfma_f32_16x16x32_f16(al[mi], bh,
                                                                accC[mi][ni], 0, 0, 0);
      }
#pragma unroll
      for (int ni = 0; ni < 4; ++ni) {
        const int rr = wn + ni * 16 + (lane & 15);
        half8 bl = *(const half8*)(Bs_l + rr * 128 + (c ^ ((rr & 7) << 4)));
#pragma unroll
        for (int mi = 0; mi < 2; ++mi)
          accC[mi][ni] = __builtin_amdgcn_mfma_f32_16x16x32_f16(ah[mi], bl,
                                                                accC[mi][ni], 0, 0, 0);
      }
    }
    __syncthreads();
  }

  // epilogue: v = accH + accC/2048 + bias, relu; stats; LN1(l0)
  float bb[4], wa0[4], wa1[4], wpv[4], gg[4], gb[4];
#pragma unroll
  for (int ni = 0; ni < 4; ++ni) {
    const int c = wn + ni * 16 + (lane & 15);
    bb[ni] = bias[c]; wa0[ni] = Wa[c]; wa1[ni] = Wa[256 + c];
    wpv[ni] = wp[c]; gg[ni] = g1[c]; gb[ni] = b1g[c];
  }
  float* red = (float*)lds;              // [5][4 colwaves][64 rows] = 5120 B
  float* muA = (float*)(lds + 5120);
  float* isA = (float*)(lds + 5376);
  const float inv = 1.f / 2048.f;
#pragma unroll
  for (int mi = 0; mi < 2; ++mi) {
#pragma unroll
    for (int reg = 0; reg < 4; ++reg) {
      const int lrow = wm + mi * 16 + (lane >> 4) * 4 + reg;
      const int row = bm + lrow;
      float v[4];
      float p0 = 0.f, p1 = 0.f, p2 = 0.f, p3 = 0.f, p4 = 0.f;
#pragma unroll
      for (int ni = 0; ni < 4; ++ni) {
        float t = accH[mi][ni][reg] + accC[mi][ni][reg] * inv + bb[ni];
        t = fmaxf(t, 0.f);
        v[ni] = t;
        p0 += t; p1 += t * wa0[ni]; p2 += t * wa1[ni]; p3 += t * wpv[ni];
        p4 += t * t;
      }
      if (row < M) {
#pragma unroll
        for (int ni = 0; ni < 4; ++ni)
          hb[(size_t)row * 256 + wn + ni * 16 + (lane & 15)] = f2bf(v[ni]);
      }
#pragma unroll
      for (int ni = 0; ni < 4; ++ni) accH[mi][ni][reg] = v[ni];
#pragma unroll
      for (int off = 1; off < 16; off <<= 1) {
        p0 += __shfl_xor(p0, off, 64);
        p1 += __shfl_xor(p1, off, 64);
        p2 += __shfl_xor(p2, off, 64);
        p3 += __shfl_xor(p3, off, 64);
        p4 += __shfl_xor(p4, off, 64);
      }
      if ((lane & 15) == 0) {
        red[(0 * 4 + (wave & 3)) * 64 + lrow] = p0;
        red[(1 * 4 + (wave & 3)) * 64 + lrow] = p1;
        red[(2 * 4 + (wave & 3)) * 64 + lrow] = p2;
        red[(3 * 4 + (wave & 3)) * 64 + lrow] = p3;
        red[(4 * 4 + (wave & 3)) * 64 + lrow] = p4;
      }
    }
  }
  __syncthreads();
  if (tid < 64) {
    float s0 = 0.f, s1 = 0.f, s2 = 0.f, s3 = 0.f, s4 = 0.f;
#pragma unroll
    for (int w = 0; w < 4; ++w) {
      s0 += red[(0 * 4 + w) * 64 + tid];
      s1 += red[(1 * 4 + w) * 64 + tid];
      s2 += red[(2 * 4 + w) * 64 + tid];
      s3 += red[(3 * 4 + w) * 64 + tid];
      s4 += red[(4 * 4 + w) * 64 + tid];
    }
    const int row = bm + tid;
    if (row < M) {
      delta[row] = s0; adst[row] = s1; asrc[row] = s2; xwp[row] = s3;
    }
    float mu = s0 * (1.f / 256.f);
    muA[tid] = mu;
    isA[tid] = rsqrtf(s4 * (1.f / 256.f) - mu * mu + 1e-5f);
  }
  __syncthreads();
#pragma unroll
  for (int mi = 0; mi < 2; ++mi) {
#pragma unroll
    for (int reg = 0; reg < 4; ++reg) {
      const int lrow = wm + mi * 16 + (lane >> 4) * 4 + reg;
      const int row = bm + lrow;
      if (row >= M) continue;
      const float mu = muA[lrow], is = isA[lrow];
#pragma unroll
      for (int ni = 0; ni < 4; ++ni) {
        const int col = wn + ni * 16 + (lane & 15);
        hn[(size_t)row * 256 + col] = f2bf((accH[mi][ni][reg] - mu) * is * gg[ni] + gb[ni]);
      }
    }
  }
}

// -------- gather-average: hagg[d] = sum_j kw[d][j] * hn[ksrc[d][j]] ----------
__global__ void gather_k(const ushort* __restrict__ hn, const int* __restrict__ ksrc,
                         const float* __restrict__ kw, ushort* __restrict__ hagg, int N) {
  int d = blockIdx.x * 8 + (threadIdx.x >> 5);
  if (d >= N) return;
  int sub = threadIdx.x & 31;
  us8 xv[8];
  float w[8];
#pragma unroll
  for (int j = 0; j < 8; ++j) {
    int s = ksrc[(size_t)d * 8 + j];
    w[j] = kw[(size_t)d * 8 + j];
    xv[j] = *reinterpret_cast<const us8*>(hn + (size_t)s * 256 + sub * 8);
  }
  float a[8] = {0.f, 0.f, 0.f, 0.f, 0.f, 0.f, 0.f, 0.f};
#pragma unroll
  for (int j = 0; j < 8; ++j)
#pragma unroll
    for (int q = 0; q < 8; ++q) a[q] += w[j] * bf2f(xv[j][q]);
  us8 o;
#pragma unroll
  for (int q = 0; q < 8; ++q) o[q] = f2bf(a[q]);
  *reinterpret_cast<us8*>(hagg + (size_t)d * 256 + sub * 8) = o;
}

// ---- conv + agg + residual + LN2, fused: 8 waves, BM=128, BN=256, K=256 -----
__launch_bounds__(512, 4)
__global__ void gemm_conv_aggln(const ushort* __restrict__ A, const ushort* __restrict__ Bt,
                                const float* __restrict__ bias, const float* __restrict__ g2,
                                const float* __restrict__ b2g, ushort* __restrict__ hb,
                                ushort* __restrict__ hn, int M) {
  __shared__ ushort As[128 * 64];   // 16 KB
  __shared__ ushort Bs[256 * 64];   // 32 KB
  const int tid = threadIdx.x;
  const int wave = tid >> 6, lane = tid & 63;
  const int bm = blockIdx.x * 128;
  const int wm = (wave >> 2) * 64, wn = (wave & 3) * 64;
  const int srow = lane >> 3;
  const int scol = (((lane & 7) ^ srow) << 3);

  f32x4 acc[4][4];
#pragma unroll
  for (int i = 0; i < 4; ++i)
#pragma unroll
    for (int j = 0; j < 4; ++j) acc[i][j] = (f32x4){0.f, 0.f, 0.f, 0.f};

  for (int k0 = 0; k0 < 256; k0 += 64) {
#pragma unroll
    for (int r = 0; r < 2; ++r) {
      const int ch = r * 8 + wave;
      int ar = bm + ch * 8 + srow;
      ar = (ar < M) ? ar : (M - 1);
      gload16(A + (size_t)ar * 256 + k0 + scol, (char*)As + ch * 1024);
    }
#pragma unroll
    for (int r = 0; r < 4; ++r) {
      const int ch = r * 8 + wave;
      const int br = ch * 8 + srow;
      gload16(Bt + (size_t)br * 256 + k0 + scol, (char*)Bs + ch * 1024);
    }
    __syncthreads();
#pragma unroll
    for (int kk = 0; kk < 2; ++kk) {
      const int c = (kk * 32 + (lane >> 4) * 8) * 2;
      short8 a[4];
#pragma unroll
      for (int mi = 0; mi < 4; ++mi) {
        const int rr = wm + mi * 16 + (lane & 15);
        a[mi] = *(const short8*)((const char*)As + rr * 128 + (c ^ ((rr & 7) << 4)));
      }
#pragma unroll
      for (int ni = 0; ni < 4; ++ni) {
        const int rr = wn + ni * 16 + (lane & 15);
        short8 b = *(const short8*)((const char*)Bs + rr * 128 + (c ^ ((rr & 7) << 4)));
#pragma unroll
        for (int mi = 0; mi < 4; ++mi)
          acc[mi][ni] = __builtin_amdgcn_mfma_f32_16x16x32_bf16(a[mi], b,
                                                                acc[mi][ni], 0, 0, 0);
      }
    }
    __syncthreads();
  }

  float bb[4];
#pragma unroll
  for (int ni = 0; ni < 4; ++ni) bb[ni] = bias[wn + ni * 16 + (lane & 15)];

  float* redS = (float*)As;            // [4 n-waves][128 rows]
  float* redQ = redS + 512;
  float* muA  = redQ + 512;            // [128]
  float* isA  = muA + 128;             // [128]

#pragma unroll
  for (int mi = 0; mi < 4; ++mi) {
#pragma unroll
    for (int reg = 0; reg < 4; ++reg) {
      const int lrow = wm + mi * 16 + (lane >> 4) * 4 + reg;
      const int row = bm + lrow;
      const bool ok = (row < M);
      float pS = 0.f, pQ = 0.f;
#pragma unroll
      for (int ni = 0; ni < 4; ++ni) {
        const int col = wn + ni * 16 + (lane & 15);
        float t = fmaxf(acc[mi][ni][reg] + bb[ni], 0.f);
        if (ok) {
          t += bf2f(hb[(size_t)row * 256 + col]);
          hb[(size_t)row * 256 + col] = f2bf(t);
        }
        acc[mi][ni][reg] = t;
        pS += t;
        pQ += t * t;
      }
#pragma unroll
      for (int off = 1; off < 16; off <<= 1) {
        pS += __shfl_xor(pS, off, 64);
        pQ += __shfl_xor(pQ, off, 64);
      }
      if ((lane & 15) == 0) {
        redS[(wave & 3) * 128 + lrow] = pS;
        redQ[(wave & 3) * 128 + lrow] = pQ;
      }
    }
  }
  __syncthreads();
  if (tid < 128) {
    float S = redS[tid] + redS[128 + tid] + redS[256 + tid] + redS[384 + tid];
    float Q = redQ[tid] + redQ[128 + tid] + redQ[256 + tid] + redQ[384 + tid];
    float mu = S * (1.f / 256.f);
    muA[tid] = mu;
    isA[tid] = rsqrtf(Q * (1.f / 256.f) - mu * mu + 1e-5f);
  }
  __syncthreads();
  float gg[4], gb[4];
#pragma unroll
  for (int ni = 0; ni < 4; ++ni) {
    gg[ni] = g2[wn + ni * 16 + (lane & 15)];
    gb[ni] = b2g[wn + ni * 16 + (lane & 15)];
  }
#pragma unroll
  for (int mi = 0; mi < 4; ++mi) {
#pragma unroll
    for (int reg = 0; reg < 4; ++reg) {
      const int lrow = wm + mi * 16 + (lane >> 4) * 4 + reg;
      const int row = bm + lrow;
      if (row >= M) continue;
      const float mu = muA[lrow], is = isA[lrow];
#pragma unroll
      for (int ni = 0; ni < 4; ++ni) {
        const int col = wn + ni * 16 + (lane & 15);
        hn[(size_t)row * 256 + col] = f2bf((acc[mi][ni][reg] - mu) * is * gg[ni] + gb[ni]);
      }
    }
  }
}

// ---- FFN1: u = gelu(hn @ W1t^T + b1). 8 waves, BM=128, BN=256 (of 512) -----
__launch_bounds__(512, 4)
__global__ void gemm_ffn1(const ushort* __restrict__ A, const ushort* __restrict__ Bt,
                          const float* __restrict__ bias, ushort* __restrict__ u, int M) {
  __shared__ ushort As[128 * 64];
  __shared__ ushort Bs[256 * 64];
  const int tid = threadIdx.x;
  const int wave = tid >> 6, lane = tid & 63;
  const int bm = blockIdx.x * 128;
  const int bn = blockIdx.y * 256;
  const int wm = (wave >> 2) * 64, wn = (wave & 3) * 64;
  const int srow = lane >> 3;
  const int scol = (((lane & 7) ^ srow) << 3);

  f32x4 acc[4][4];
#pragma unroll
  for (int i = 0; i < 4; ++i)
#pragma unroll
    for (int j = 0; j < 4; ++j) acc[i][j] = (f32x4){0.f, 0.f, 0.f, 0.f};

  for (int k0 = 0; k0 < 256; k0 += 64) {
#pragma unroll
    for (int r = 0; r < 2; ++r) {
      const int ch = r * 8 + wave;
      int ar = bm + ch * 8 + srow;
      ar = (ar < M) ? ar : (M - 1);
      gload16(A + (size_t)ar * 256 + k0 + scol, (char*)As + ch * 1024);
    }
#pragma unroll
    for (int r = 0; r < 4; ++r) {
      const int ch = r * 8 + wave;
      const int br = bn + ch * 8 + srow;
      gload16(Bt + (size_t)br * 256 + k0 + scol, (char*)Bs + ch * 1024);
    }
    __syncthreads();
#pragma unroll
    for (int kk = 0; kk < 2; ++kk) {
      const int c = (kk * 32 + (lane >> 4) * 8) * 2;
      short8 a[4];
#pragma unroll
      for (int mi = 0; mi < 4; ++mi) {
        const int rr = wm + mi * 16 + (lane & 15);
        a[mi] = *(const short8*)((const char*)As + rr * 128 + (c ^ ((rr & 7) << 4)));
      }
#pragma unroll
      for (int ni = 0; ni < 4; ++ni) {
        const int rr = wn + ni * 16 + (lane & 15);
        short8 b = *(const short8*)((const char*)Bs + rr * 128 + (c ^ ((rr & 7) << 4)));
#pragma unroll
        for (int mi = 0; mi < 4; ++mi)
          acc[mi][ni] = __builtin_amdgcn_mfma_f32_16x16x32_bf16(a[mi], b,
                                                                acc[mi][ni], 0, 0, 0);
      }
    }
    __syncthreads();
  }

  float bb[4];
#pragma unroll
  for (int ni = 0; ni < 4; ++ni) bb[ni] = bias[bn + wn + ni * 16 + (lane & 15)];
#pragma unroll
  for (int mi = 0; mi < 4; ++mi) {
#pragma unroll
    for (int reg = 0; reg < 4; ++reg) {
      const int row = bm + wm + mi * 16 + (lane >> 4) * 4 + reg;
      if (row >= M) continue;
#pragma unroll
      for (int ni = 0; ni < 4; ++ni) {
        const int col = bn + wn + ni * 16 + (lane & 15);
        u[(size_t)row * 512 + col] = f2bf(gelu_f(acc[mi][ni][reg] + bb[ni]));
      }
    }
  }
}

// -------- fused FFN2 + residual + LN1_{l+1}: 8 waves, tile 128x256, K=512 ----
template <int LAST>
__launch_bounds__(512, 4)
__global__ void gemm_ffn2ln(const ushort* __restrict__ A, const ushort* __restrict__ Bt,
                            const float* __restrict__ bias, const float* __restrict__ g1,
                            const float* __restrict__ b1g, ushort* __restrict__ hb,
                            ushort* __restrict__ hn, int M) {
  __shared__ ushort As[128 * 64];   // 16 KB
  __shared__ ushort Bs[256 * 64];   // 32 KB
  const int tid = threadIdx.x;
  const int wave = tid >> 6, lane = tid & 63;
  const int bm = blockIdx.x * 128;
  const int wm = (wave >> 2) * 64, wn = (wave & 3) * 64;
  const int srow = lane >> 3;
  const int scol = (((lane & 7) ^ srow) << 3);

  f32x4 acc[4][4];
#pragma unroll
  for (int i = 0; i < 4; ++i)
#pragma unroll
    for (int j = 0; j < 4; ++j) acc[i][j] = (f32x4){0.f, 0.f, 0.f, 0.f};

  for (int k0 = 0; k0 < 512; k0 += 64) {
#pragma unroll
    for (int r = 0; r < 2; ++r) {
      const int ch = r * 8 + wave;
      int ar = bm + ch * 8 + srow;
      ar = (ar < M) ? ar : (M - 1);
      gload16(A + (size_t)ar * 512 + k0 + scol, (char*)As + ch * 1024);
    }
#pragma unroll
    for (int r = 0; r < 4; ++r) {
      const int ch = r * 8 + wave;
      const int br = ch * 8 + srow;
      gload16(Bt + (size_t)br * 512 + k0 + scol, (char*)Bs + ch * 1024);
    }
    __syncthreads();
#pragma unroll
    for (int kk = 0; kk < 2; ++kk) {
      const int c = (kk * 32 + (lane >> 4) * 8) * 2;
      short8 a[4];
#pragma unroll
      for (int mi = 0; mi < 4; ++mi) {
        const int rr = wm + mi * 16 + (lane & 15);
        a[mi] = *(const short8*)((const char*)As + rr * 128 + (c ^ ((rr & 7) << 4)));
      }
#pragma unroll
      for (int ni = 0; ni < 4; ++ni) {
        const int rr = wn + ni * 16 + (lane & 15);
        short8 b = *(const short8*)((const char*)Bs + rr * 128 + (c ^ ((rr & 7) << 4)));
#pragma unroll
        for (int mi = 0; mi < 4; ++mi)
          acc[mi][ni] = __builtin_amdgcn_mfma_f32_16x16x32_bf16(a[mi], b,
                                                                acc[mi][ni], 0, 0, 0);
      }
    }
    __syncthreads();
  }

  float bb[4];
#pragma unroll
  for (int ni = 0; ni < 4; ++ni) bb[ni] = bias[wn + ni * 16 + (lane & 15)];

  float* redS = (float*)As;            // [4 n-waves][128 rows]
  float* redQ = redS + 512;
  float* muA  = redQ + 512;            // [128]
  float* isA  = muA + 128;             // [128]

#pragma unroll
  for (int mi = 0; mi < 4; ++mi) {
#pragma unroll
    for (int reg = 0; reg < 4; ++reg) {
      const int lrow = wm + mi * 16 + (lane >> 4) * 4 + reg;
      const int row = bm + lrow;
      const bool ok = (row < M);
      float pS = 0.f, pQ = 0.f;
#pragma unroll
      for (int ni = 0; ni < 4; ++ni) {
        const int col = wn + ni * 16 + (lane & 15);
        float t = acc[mi][ni][reg] + bb[ni];
        if (ok) t += bf2f(hb[(size_t)row * 256 + col]);
        acc[mi][ni][reg] = t;
        if (LAST) {
          if (ok) hn[(size_t)row * 256 + col] = f2bf(t);
        } else {
          if (ok) hb[(size_t)row * 256 + col] = f2bf(t);
          pS += t;
          pQ += t * t;
        }
      }
      if (!LAST) {
#pragma unroll
        for (int off = 1; off < 16; off <<= 1) {
          pS += __shfl_xor(pS, off, 64);
          pQ += __shfl_xor(pQ, off, 64);
        }
        if ((lane & 15) == 0) {
          redS[(wave & 3) * 128 + lrow] = pS;
          redQ[(wave & 3) * 128 + lrow] = pQ;
        }
      }
    }
  }
  if (LAST) return;
  __syncthreads();
  if (tid < 128) {
    float S = redS[tid] + redS[128 + tid] + redS[256 + tid] + redS[384 + tid];
    float Q = redQ[tid] + redQ[128 + tid] + redQ[256 + tid] + redQ[384 + tid];
    float mu = S * (1.f / 256.f);
    muA[tid] = mu;
    isA[tid] = rsqrtf(Q * (1.f / 256.f) - mu * mu + 1e-5f);
  }
  __syncthreads();
  float gg[4], gb[4];
#pragma unroll
  for (int ni = 0; ni < 4; ++ni) {
    gg[ni] = g1[wn + ni * 16 + (lane & 15)];
    gb[ni] = b1g[wn + ni * 16 + (lane & 15)];
  }
#pragma unroll
  for (int mi = 0; mi < 4; ++mi) {
#pragma unroll
    for (int reg = 0; reg < 4; ++reg) {
      const int lrow = wm + mi * 16 + (lane >> 4) * 4 + reg;
      const int row = bm + lrow;
      if (row >= M) continue;
      const float mu = muA[lrow], is = isA[lrow];
#pragma unroll
      for (int ni = 0; ni < 4; ++ni) {
        const int col = wn + ni * 16 + (lane & 15);
        hn[(size_t)row * 256 + col] = f2bf((acc[mi][ni][reg] - mu) * is * gg[ni] + gb[ni]);
      }
    }
  }
}

// ---------------- bf16 MFMA output GEMM: C(f32) = A @ Bt^T + bias ------------
__launch_bounds__(256)
__global__ void gemm_out(const ushort* __restrict__ A, const ushort* __restrict__ Bt,
                         const float* __restrict__ bias, float* __restrict__ C, int M) {
  __shared__ ushort As[128 * 64];
  __shared__ ushort Bs[64 * 64];
  const int tid = threadIdx.x;
  const int wave = tid >> 6, lane = tid & 63;
  const int bm = blockIdx.x * 128;
  const int wm = wave * 32;
  const int srow = lane >> 3;
  const int scol = (((lane & 7) ^ srow) << 3);
  f32x4 acc[2][4];
#pragma unroll
  for (int i = 0; i < 2; ++i)
#pragma unroll
    for (int j = 0; j < 4; ++j) acc[i][j] = (f32x4){0.f, 0.f, 0.f, 0.f};

  for (int k0 = 0; k0 < 256; k0 += 64) {
#pragma unroll
    for (int r = 0; r < 4; ++r) {
      const int ch = r * 4 + wave;
      int ar = bm + ch * 8 + srow;
      ar = (ar < M) ? ar : (M - 1);
      gload16(A + (size_t)ar * 256 + k0 + scol, (char*)As + ch * 1024);
    }
#pragma unroll
    for (int r = 0; r < 2; ++r) {
      const int ch = r * 4 + wave;
      const int br = ch * 8 + srow;
      gload16(Bt + (size_t)br * 256 + k0 + scol, (char*)Bs + ch * 1024);
    }
    __syncthreads();
#pragma unroll
    for (int kk = 0; kk < 2; ++kk) {
      const int c = (kk * 32 + (lane >> 4) * 8) * 2;
      short8 a[2], b[4];
#pragma unroll
      for (int mi = 0; mi < 2; ++mi) {
        const int rr = wm + mi * 16 + (lane & 15);
        a[mi] = *(const short8*)((const char*)As + rr * 128 + (c ^ ((rr & 7) << 4)));
      }
#pragma unroll
      for (int ni = 0; ni < 4; ++ni) {
        const int rr = ni * 16 + (lane & 15);
        b[ni] = *(const short8*)((const char*)Bs + rr * 128 + (c ^ ((rr & 7) << 4)));
      }
#pragma unroll
      for (int mi = 0; mi < 2; ++mi)
#pragma unroll
        for (int ni = 0; ni < 4; ++ni)
          acc[mi][ni] = __builtin_amdgcn_mfma_f32_16x16x32_bf16(a[mi], b[ni],
                                                                acc[mi][ni], 0, 0, 0);
    }
    __syncthreads();
  }
  float bb[4];
#pragma unroll
  for (int ni = 0; ni < 4; ++ni) bb[ni] = bias[ni * 16 + (lane & 15)];
#pragma unroll
  for (int mi = 0; mi < 2; ++mi) {
#pragma unroll
    for (int reg = 0; reg < 4; ++reg) {
      const int row = bm + wm + mi * 16 + (lane >> 4) * 4 + reg;
      if (row >= M) continue;
#pragma unroll
      for (int ni = 0; ni < 4; ++ni) {
        const int col = ni * 16 + (lane & 15);
        C[(size_t)row * 64 + col] = acc[mi][ni][reg] + bb[ni];
      }
    }
  }
}

// ---- one-shot prep: weight transposes/converts (incl. Wi f16 split) + zero --
#define W_IN 65536
#define W_TOTAL (196608 + 393216 + 393216 + 16384)
__global__ void prep_k(const float* __restrict__ Wi, const float* __restrict__ Wc,
                       const float* __restrict__ W1, const float* __restrict__ W2,
                       const float* __restrict__ Wo, _Float16* __restrict__ WiTh,
                       _Float16* __restrict__ WiTl, ushort* __restrict__ WcT,
                       ushort* __restrict__ W1T, ushort* __restrict__ W2T,
                       ushort* __restrict__ WoT, float* __restrict__ zbase, int zn) {
  int i = blockIdx.x * 256 + threadIdx.x;
  if (i < W_IN) {
    int n = i >> 8, k = i & 255;
    float w = Wi[(size_t)k * 256 + n];
    _Float16 hv = (_Float16)w;
    WiTh[i] = hv;
    WiTl[i] = (_Float16)((w - (float)hv) * 2048.f);
  } else if ((i -= W_IN) < W_TOTAL) {
    int j = i;
    if (j < 196608) {
      int l = j / 65536, r = j % 65536, n = r >> 8, k = r & 255;
      WcT[j] = f2bf(Wc[(size_t)l * 65536 + k * 256 + n]);
    } else if ((j -= 196608) < 393216) {
      int l = j / 131072, r = j % 131072, n = r >> 8, k = r & 255;
      W1T[j] = f2bf(W1[(size_t)l * 131072 + k * 512 + n]);
    } else if ((j -= 393216) < 393216) {
      int l = j / 131072, r = j % 131072, n = r >> 9, k = r & 511;
      W2T[j] = f2bf(W2[(size_t)l * 131072 + k * 256 + n]);
    } else {
      j -= 393216;
      int n = j >> 8, k = j & 255;
      WoT[j] = f2bf(Wo[k * 64 + n]);
    }
  } else {
    int z = i - W_TOTAL;
    if (z < zn) zbase[z] = 0.f;
  }
}

__global__ void neigh_k(const int* __restrict__ src, const int* __restrict__ dst,
                        const float* __restrict__ delta, float* __restrict__ neigh, int E) {
  int e = blockIdx.x * 256 + threadIdx.x;
  if (e < E) atomicAdd(&neigh[dst[e]], delta[src[e]]);
}

// edge logits (pi inline); slots layout [t][N]
__global__ void logits_k(const int* __restrict__ src, const int* __restrict__ dst,
                         const float* __restrict__ adst, const float* __restrict__ asrc,
                         const float* __restrict__ xwp, const float* __restrict__ neigh,
                         const float* __restrict__ Wa, const float* __restrict__ ba,
                         float* __restrict__ expe, float* __restrict__ denom,
                         int* __restrict__ cnt, int* __restrict__ slots,
                         int E, int Et, int N) {
  int e = blockIdx.x * 256 + threadIdx.x;
  if (e >= Et) return;
  int s, d;
  if (e < E) { s = src[e]; d = dst[e]; } else { s = e - E; d = s; }
  float pis = 1.f / (1.f + expf(-(xwp[s] + neigh[s])));
  float v = adst[d] + asrc[s] + pis * Wa[512] + ba[0];
  v = (v >= 0.f ? v : 0.2f * v) / TAUF;
  v = fminf(fmaxf(v, -5.f), 5.f);
  float ex = expf(v);
  expe[e] = ex;
  atomicAdd(&denom[d], ex);
  int p = atomicAdd(&cnt[d], 1);
  if (p < 64) slots[(size_t)p * N + d] = e;
}

__device__ __forceinline__ bool better(float a, int e, float a2, int e2) {
  return a > a2 || (a == a2 && e < e2);
}

// top-8 + renormalize; ksrc/kw padded to exactly 8 entries (w=0)
__global__ void topk_k(const int* __restrict__ cnt, const int* __restrict__ slots,
                       const float* __restrict__ expe, const float* __restrict__ denom,
                       const int* __restrict__ src, int* __restrict__ ksrc,
                       float* __restrict__ kw, int N, int E) {
  int d = blockIdx.x * 256 + threadIdx.x;
  if (d >= N) return;
  int deg = min(cnt[d], 64);
  float D = denom[d] + 1e-16f;
  float av[8]; int ai[8]; int kc = 0;
  for (int t = 0; t < deg; ++t) {
    int e = slots[(size_t)t * N + d];
    float a = expe[e] / D;
    if (kc < 8) {
      int p = kc++;
      while (p > 0 && better(a, e, av[p - 1], ai[p - 1])) {
        av[p] = av[p - 1]; ai[p] = ai[p - 1]; --p;
      }
      av[p] = a; ai[p] = e;
    } else if (better(a, e, av[7], ai[7])) {
      int p = 7;
      while (p > 0 && better(a, e, av[p - 1], ai[p - 1])) {
        av[p] = av[p - 1]; ai[p] = ai[p - 1]; --p;
      }
      av[p] = a; ai[p] = e;
    }
  }
  float ks = 0.f;
  for (int j = 0; j < kc; ++j) ks += av[j];
  float inv = 1.f / (ks + 1e-16f);
#pragma unroll
  for (int j = 0; j < 8; ++j) {
    if (j < kc) {
      int e = ai[j];
      ksrc[(size_t)d * 8 + j] = (e < E) ? src[e] : (e - E);
      kw[(size_t)d * 8 + j] = av[j] * inv;
    } else {
      ksrc[(size_t)d * 8 + j] = 0;
      kw[(size_t)d * 8 + j] = 0.f;
    }
  }
}

extern "C" void kernel_launch(void* const* d_in, const int* in_sizes, int n_in,
                              void* d_out, int out_size, void* d_ws, size_t ws_size,
                              hipStream_t stream) {
  const float* X   = (const float*)d_in[0];
  const int*   EI  = (const int*)d_in[1];
  const float* Wi  = (const float*)d_in[2];
  const float* bi  = (const float*)d_in[3];
  const float* wp  = (const float*)d_in[4];
  const float* Wa  = (const float*)d_in[5];
  const float* ba  = (const float*)d_in[6];
  const float* l1g = (const float*)d_in[7];
  const float* l1b = (const float*)d_in[8];
  const float* l2g = (const float*)d_in[9];
  const float* l2b = (const float*)d_in[10];
  const float* W1  = (const float*)d_in[11];
  const float* b1  = (const float*)d_in[12];
  const float* W2  = (const float*)d_in[13];
  const float* b2  = (const float*)d_in[14];
  const float* Wc  = (const float*)d_in[15];
  const float* bc  = (const float*)d_in[16];
  const float* Wo  = (const float*)d_in[17];
  const float* bo  = (const float*)d_in[18];

  const int N = in_sizes[0] / 256;
  const int E = in_sizes[1] / 2;
  const int Et = E + N;
  const int* srcp = EI;
  const int* dstp = EI + E;

  float* ws = (float*)d_ws;
  size_t off = 0;
  auto alloc = [&](size_t n) { float* p = ws + off; off += n; return p; };
  const size_t NH = (size_t)N * 256;
  ushort* hb   = (ushort*)alloc(NH / 2);               // bf16 residual [N][256]
  ushort* hn   = (ushort*)alloc(NH / 2);               // bf16 [N][256]
  ushort* hagg = (ushort*)alloc(NH / 2);               // bf16 [N][256]
  ushort* u    = (ushort*)alloc(NH);                   // bf16 [N][512]
  _Float16* WiTh = (_Float16*)alloc(65536 / 2);
  _Float16* WiTl = (_Float16*)alloc(65536 / 2);
  ushort* WcT  = (ushort*)alloc(3 * 65536 / 2);
  ushort* W1T  = (ushort*)alloc(3 * 131072 / 2);
  ushort* W2T  = (ushort*)alloc(3 * 131072 / 2);
  ushort* WoT  = (ushort*)alloc(16384 / 2);
  float* delta = alloc(N);
  float* adst  = alloc(N);
  float* asrc  = alloc(N);
  float* xwp   = alloc(N);
  float* expe  = alloc(Et);
  float* neigh = alloc(N);       // ┐ contiguous zero region (3N)
  float* denom = alloc(N);       // │
  int*   cnt   = (int*)alloc(N); // ┘
  int*   slots = (int*)alloc((size_t)N * 64);
  int*   ksrc  = (int*)alloc((size_t)N * 8);
  float* kw    = alloc((size_t)N * 8);

  prep_k<<<(W_IN + W_TOTAL + 3 * N + 255) / 256, 256, 0, stream>>>(
      Wi, Wc, W1, W2, Wo, WiTh, WiTl, WcT, W1T, W2T, WoT, neigh, 3 * N);

  // input projection + relu + row stats + LN1(l0); X split fused into staging
  gemm_in_mfma<<<(N + 63) / 64, 512, 0, stream>>>(
      X, WiTh, WiTl, bi, Wa, wp, l1g, l1b, hb, hn,
      delta, adst, asrc, xwp, N);
  neigh_k<<<(E + 255) / 256, 256, 0, stream>>>(srcp, dstp, delta, neigh, E);
  logits_k<<<(Et + 255) / 256, 256, 0, stream>>>(srcp, dstp, adst, asrc, xwp, neigh,
                                                 Wa, ba, expe, denom, cnt, slots,
                                                 E, Et, N);
  topk_k<<<(N + 255) / 256, 256, 0, stream>>>(cnt, slots, expe, denom, srcp,
                                              ksrc, kw, N, E);

  const int GM = (N + 127) / 128;
  for (int l = 0; l < 3; ++l) {
    gather_k<<<(N + 7) / 8, 256, 0, stream>>>(hn, ksrc, kw, hagg, N);
    gemm_conv_aggln<<<GM, 512, 0, stream>>>(
        hagg, WcT + (size_t)l * 65536, bc + l * 256,
        l2g + l * 256, l2b + l * 256, hb, hn, N);
    gemm_ffn1<<<dim3(GM, 2), 512, 0, stream>>>(
        hn, W1T + (size_t)l * 131072, b1 + l * 512, u, N);
    if (l < 2)
      gemm_ffn2ln<0><<<GM, 512, 0, stream>>>(
          u, W2T + (size_t)l * 131072, b2 + l * 256,
          l1g + (l + 1) * 256, l1b + (l + 1) * 256, hb, hn, N);
    else
      gemm_ffn2ln<1><<<GM, 512, 0, stream>>>(
          u, W2T + (size_t)l * 131072, b2 + l * 256,
          nullptr, nullptr, hb, hn, N);
  }
  gemm_out<<<(N + 127) / 128, 256, 0, stream>>>(hn, WoT, bo, (float*)d_out, N);
}